// Round 12
// baseline (622.327 us; speedup 1.0000x reference)
//
#include <hip/hip_runtime.h>

#define EPS 1e-3f

// Tensor geometry (fixed for this problem):
// y1 (L1 pre-act): quad-interleaved (2, 4, 21,256,256, 4) = (b, c/4, z,y,x, c%4)
// m1: (2,21,256,256);  bm2: (2,11,128,128) uint32 active-tap bitmask (27 bits)
// h2q: quad-interleaved (2, 8, 11,128,128, 4)   m2: (2,11,128,128)
// h3:  (2,64,5,64,64)  m3: (2,5,64,64)
// out: (2,64,2,64,64) -> d_out (2,128,64,64) same layout
//
// Lessons encoded:
//  - Block-uniform or well-coalesced weight access only. (r2)
//  - Direct conv beats phase-barrier LDS staging for these shapes. (r10)
//  - m1 density 4.3%: per-LANE mask tests are divergence-doomed (94% of waves
//    execute a tap for ~3/64 lanes -> 59us of dense-issue FMA for 3us of work,
//    r11). Fix: per-px active-tap BITMASK (built in a dense amortized pass) +
//    one WAVE per px so ctz-driven tap skip is exec-uniform. (r12)
//  - conv_l3 8-way oc-split duplicated h2 L2 reads 8x -> use 4. (r11)

// ---------------- Weight repack + BN fold ----------------
// wT2: [tap][oc][cin] 27x32x16; wT3: [tap][cin][oc] 27x32x64; wT4: [(c*3+kz)*64+oc]
// shb: [0..31]=sh2, [32..95]=sh3, [96..159]=sh4, [160..175]=sc1, [176..191]=sh1
__global__ __launch_bounds__(256) void repack(
    const float* __restrict__ g1, const float* __restrict__ b1,
    const float* __restrict__ rm1, const float* __restrict__ rv1,
    const float* __restrict__ w2, const float* __restrict__ g2, const float* __restrict__ b2,
    const float* __restrict__ rm2, const float* __restrict__ rv2,
    const float* __restrict__ w3, const float* __restrict__ g3, const float* __restrict__ b3,
    const float* __restrict__ rm3, const float* __restrict__ rv3,
    const float* __restrict__ w4, const float* __restrict__ g4, const float* __restrict__ b4,
    const float* __restrict__ rm4, const float* __restrict__ rv4,
    float* __restrict__ wT2, float* __restrict__ wT3, float* __restrict__ wT4,
    float* __restrict__ shb)
{
    const int i = blockIdx.x * 256 + threadIdx.x;
    if (i < 13824) {                       // wT2[tap*512 + oc*16 + cin]
        const int tap = i / 512, oc = (i % 512) / 16, cin = i & 15;
        const float inv = g2[oc] * rsqrtf(rv2[oc] + EPS);
        wT2[i] = w2[(oc * 16 + cin) * 27 + tap] * inv;
    } else if (i < 69120) {                // wT3[tap*2048 + cin*64 + oc]
        const int j = i - 13824;
        const int tap = j / 2048, cin = (j / 64) % 32, oc = j & 63;
        const float inv = g3[oc] * rsqrtf(rv3[oc] + EPS);
        wT3[j] = w3[(oc * 32 + cin) * 27 + tap] * inv;
    } else if (i < 81408) {                // wT4[(c*3+kz)*64+oc], 64x3x64
        const int j = i - 69120;
        const int c = j / 192, kz = (j / 64) % 3, oc = j & 63;
        const float inv = g4[oc] * rsqrtf(rv4[oc] + EPS);
        wT4[j] = w4[(oc * 64 + c) * 3 + kz] * inv;
    } else if (i < 81600) {                // shifts + L1 BN scale/shift
        const int j = i - 81408;
        if (j < 32) {
            const float inv = g2[j] * rsqrtf(rv2[j] + EPS);
            shb[j] = b2[j] - rm2[j] * inv;
        } else if (j < 96) {
            const int o = j - 32;
            const float inv = g3[o] * rsqrtf(rv3[o] + EPS);
            shb[j] = b3[o] - rm3[o] * inv;
        } else if (j < 160) {
            const int o = j - 96;
            const float inv = g4[o] * rsqrtf(rv4[o] + EPS);
            shb[j] = b4[o] - rm4[o] * inv;
        } else if (j < 176) {
            const int o = j - 160;
            shb[j] = g1[o] * rsqrtf(rv1[o] + EPS);           // sc1
        } else if (j < 192) {
            const int o = j - 176;
            const float inv = g1[o] * rsqrtf(rv1[o] + EPS);
            shb[j] = b1[o] - rm1[o] * inv;                   // sh1
        }
    }
}

// ---------------- Layer 1: voxel scatter, one thread per (voxel, oc) ----------------
__global__ __launch_bounds__(256) void scatter_l1(
    const float* __restrict__ vf, const int* __restrict__ coors, int NV,
    const float* __restrict__ w1, float* __restrict__ y1, float* __restrict__ m1)
{
    __shared__ float ws[16 * 3 * 27];  // (oc, c, tap)
    for (int e = threadIdx.x; e < 16 * 3 * 27; e += 256) ws[e] = w1[e];
    __syncthreads();

    const int gid = blockIdx.x * 256 + threadIdx.x;
    const int i = gid >> 4;        // voxel
    const int oc = gid & 15;       // channel
    if (i >= NV) return;
    const int oc4 = oc >> 2, ocl = oc & 3;

    const int b = coors[4 * i + 0];
    const int z = coors[4 * i + 1];
    const int y = coors[4 * i + 2];
    const int x = coors[4 * i + 3];
    const float f0 = vf[3 * i + 0];
    const float f1 = vf[3 * i + 1];
    const float f2 = vf[3 * i + 2];

    int ozv[2], kzv[2], nz = 0;
    int oyv[2], kyv[2], ny = 0;
    int oxv[2], kxv[2], nx = 0;
#pragma unroll
    for (int k = 0; k < 3; ++k) {
        int t = z + 1 - k;
        if (t >= 0 && !(t & 1)) { int o = t >> 1; if (o < 21) { ozv[nz] = o; kzv[nz] = k; ++nz; } }
    }
#pragma unroll
    for (int k = 0; k < 3; ++k) {
        int t = y + 1 - k;
        if (t >= 0 && !(t & 1)) { int o = t >> 1; if (o < 256) { oyv[ny] = o; kyv[ny] = k; ++ny; } }
    }
#pragma unroll
    for (int k = 0; k < 3; ++k) {
        int t = x + 1 - k;
        if (t >= 0 && !(t & 1)) { int o = t >> 1; if (o < 256) { oxv[nx] = o; kxv[nx] = k; ++nx; } }
    }

    for (int a = 0; a < nz; ++a)
        for (int bb = 0; bb < ny; ++bb)
            for (int c = 0; c < nx; ++c) {
                const int oz = ozv[a], oy = oyv[bb], ox = oxv[c];
                const int tap = (kzv[a] * 3 + kyv[bb]) * 3 + kxv[c];
                const int sp = oz * 65536 + oy * 256 + ox;
                if (oc == 0) m1[b * 1376256 + sp] = 1.0f;
                const float s = ws[oc * 81 + tap] * f0 + ws[oc * 81 + 27 + tap] * f1 +
                                ws[oc * 81 + 54 + tap] * f2;
                atomicAdd(&y1[(b * 4 + oc4) * 5505024 + sp * 4 + ocl], s);
            }
}

// ---------------- Build per-l2-px active-tap bitmask (dense, amortized) ----------------
__global__ __launch_bounds__(256) void build_bm2(
    const float* __restrict__ m1, unsigned* __restrict__ bm2)
{
    const int idx = blockIdx.x * 256 + threadIdx.x;       // < 360448
    if (idx >= 360448) return;
    const int b = idx / 180224;
    const int r = idx - b * 180224;
    const int oz = r / 16384, r2 = r & 16383, oy = r2 >> 7, ox = r2 & 127;
    const int iz0 = 2 * oz - 1, iyb = 2 * oy - 1, ixb = 2 * ox - 1;

    unsigned bm = 0;
#pragma unroll
    for (int kz = 0; kz < 3; ++kz) {
        const int iz = iz0 + kz;
#pragma unroll
        for (int ky = 0; ky < 3; ++ky) {
            const int iy = iyb + ky;
#pragma unroll
            for (int kx = 0; kx < 3; ++kx) {
                const int ix = ixb + kx;
                if ((unsigned)iz < 21u && (unsigned)iy < 256u && (unsigned)ix < 256u) {
                    const float m = m1[b * 1376256 + iz * 65536 + iy * 256 + ix];
                    if (m > 0.f) bm |= 1u << ((kz * 3 + ky) * 3 + kx);
                }
            }
        }
    }
    bm2[idx] = bm;
}

// ---------------- Layer 2: sparse conv 16->32 via bitmask, ONE WAVE PER PX ----------------
// 64 lanes = 32 oc x 2 cin-halves. Tap loop driven by ctz(bm): bm identical
// across lanes -> exec-uniform skip; only truly active taps (~1.2/27) issue.
__global__ __launch_bounds__(256) void conv_l2(
    const float4* __restrict__ y1q, const unsigned* __restrict__ bm2,
    const float4* __restrict__ wT2q, const float* __restrict__ shb,
    float* __restrict__ h2, float* __restrict__ m2)
{
    const int tid = threadIdx.x;
    const int wv = tid >> 6, lane = tid & 63;
    const int oc = lane & 31, half = lane >> 5;
    const int ox = blockIdx.x * 4 + wv;                // 0..127
    const int oy = blockIdx.y;                         // 0..127
    const int b = blockIdx.z / 11, oz = blockIdx.z % 11;
    const int spo = oz * 16384 + oy * 128 + ox;
    const int iz0 = 2 * oz - 1, iyb = 2 * oy - 1, ixb = 2 * ox - 1;

    const unsigned bm0 = bm2[b * 180224 + spo];
    unsigned bm = bm0;

    // this lane's 8 cin BN params (cin = half*8 + 0..7)
    const float4* shb4 = (const float4*)shb;
    const float4 sca = shb4[40 + half * 2], scb = shb4[41 + half * 2];
    const float4 sha = shb4[44 + half * 2], shc = shb4[45 + half * 2];

    float acc = 0.f;
    while (bm) {
        const int tap = __builtin_ctz(bm);
        bm &= bm - 1;
        const int kz = tap / 9, rr = tap - kz * 9, ky = rr / 3, kx = rr - ky * 3;
        const int sp = (iz0 + kz) * 65536 + (iyb + ky) * 256 + (ixb + kx);
        // bm bit set => cell active => in-bounds by construction
        const float4 a0 = y1q[(b * 4 + half * 2 + 0) * 1376256 + sp];
        const float4 a1 = y1q[(b * 4 + half * 2 + 1) * 1376256 + sp];
        const float v0 = fmaxf(a0.x * sca.x + sha.x, 0.f);
        const float v1 = fmaxf(a0.y * sca.y + sha.y, 0.f);
        const float v2 = fmaxf(a0.z * sca.z + sha.z, 0.f);
        const float v3 = fmaxf(a0.w * sca.w + sha.w, 0.f);
        const float v4 = fmaxf(a1.x * scb.x + shc.x, 0.f);
        const float v5 = fmaxf(a1.y * scb.y + shc.y, 0.f);
        const float v6 = fmaxf(a1.z * scb.z + shc.z, 0.f);
        const float v7 = fmaxf(a1.w * scb.w + shc.w, 0.f);
        const float4 w0 = wT2q[(tap * 32 + oc) * 4 + half * 2 + 0];
        const float4 w1 = wT2q[(tap * 32 + oc) * 4 + half * 2 + 1];
        acc = fmaf(w0.x, v0, fmaf(w0.y, v1, fmaf(w0.z, v2, fmaf(w0.w, v3,
              fmaf(w1.x, v4, fmaf(w1.y, v5, fmaf(w1.z, v6, fmaf(w1.w, v7, acc))))))));
    }

    const float other = __shfl_xor(acc, 32);
    const float mout = bm0 ? 1.f : 0.f;
    if (half == 0) {
        const float val = fmaxf(acc + other + shb[oc], 0.f) * mout;
        h2[(b * 8 + (oc >> 2)) * 720896 + spo * 4 + (oc & 3)] = val;
    }
    if (lane == 0) m2[b * 180224 + spo] = mout;
}

// ---------------- Layer 3: DIRECT conv 32->64, k3, s2, pad(0,1,1) ----------------
// One thread per (output px, 16-oc group): 4-way oc split (halved L2 dup vs r11).
__global__ __launch_bounds__(128) __attribute__((amdgpu_waves_per_eu(4, 8)))
void conv_l3(
    const float4* __restrict__ h2q, const float* __restrict__ m2,
    const float* __restrict__ wT3, const float* __restrict__ shb,
    float* __restrict__ h3, float* __restrict__ m3)
{
    const int tid = threadIdx.x;
    const int tx = tid & 15, ty = tid >> 4;            // 16 x 8 px tile
    const int ocg = blockIdx.x >> 2;                   // 0..3 (16 oc each)
    const int ox = (blockIdx.x & 3) * 16 + tx, oy = blockIdx.y * 8 + ty;
    const int bz = blockIdx.z;
    const int b = bz / 5, oz = bz % 5;
    const int iz0 = 2 * oz, iyb = 2 * oy - 1, ixb = 2 * ox - 1;   // z pad 0

    float acc[16];
#pragma unroll
    for (int oc = 0; oc < 16; ++oc) acc[oc] = 0.f;
    float msum = 0.f;

#pragma unroll 1
    for (int kz = 0; kz < 3; ++kz) {
        const int iz = iz0 + kz;                       // always in [0,10]
#pragma unroll 1
        for (int ky = 0; ky < 3; ++ky) {
            const int iy = iyb + ky;
#pragma unroll 1
            for (int kx = 0; kx < 3; ++kx) {
                const int ix = ixb + kx;
                const bool ok = (unsigned)iy < 128u && (unsigned)ix < 128u;
                if (ok) {
                    const int sp = iz * 16384 + iy * 128 + ix;
                    msum += m2[b * 180224 + sp];
                    const int tap = (kz * 3 + ky) * 3 + kx;
                    const float* __restrict__ wq = wT3 + tap * 2048 + ocg * 16; // uniform
#pragma unroll
                    for (int q = 0; q < 8; ++q) {
                        const float4 a = h2q[(b * 8 + q) * 180224 + sp];
                        const int c0 = q * 4;
#pragma unroll
                        for (int oc = 0; oc < 16; ++oc) {
                            acc[oc] = fmaf(wq[(c0 + 0) * 64 + oc], a.x,
                                      fmaf(wq[(c0 + 1) * 64 + oc], a.y,
                                      fmaf(wq[(c0 + 2) * 64 + oc], a.z,
                                      fmaf(wq[(c0 + 3) * 64 + oc], a.w, acc[oc]))));
                        }
                    }
                }
            }
        }
    }

    const float mout = msum > 0.f ? 1.f : 0.f;
    const int spo = oz * 4096 + oy * 64 + ox;
    if (ocg == 0) m3[b * 20480 + spo] = mout;
#pragma unroll
    for (int oc = 0; oc < 16; ++oc) {
        const int ocg16 = ocg * 16 + oc;
        h3[(b * 64 + ocg16) * 20480 + spo] =
            fmaxf(acc[oc] + shb[32 + ocg16], 0.f) * mout;
    }
}

// ---------------- Layer 4: conv 64->64, k(3,1,1), s(2,1,1), pad 0 ----------------
__global__ __launch_bounds__(256) __attribute__((amdgpu_waves_per_eu(4, 8)))
void conv_l4(
    const float* __restrict__ h3, const float* __restrict__ m3,
    const float* __restrict__ wT4, const float* __restrict__ shb,
    float* __restrict__ out)
{
    const int p = blockIdx.x * 256 + threadIdx.x;  // 0..4095 spatial
    const int bo = blockIdx.y;
    const int b = bo >> 4, od = (bo >> 3) & 1, ocg = bo & 7;

    const float msum = m3[(b * 5 + 2 * od + 0) * 4096 + p] +
                       m3[(b * 5 + 2 * od + 1) * 4096 + p] +
                       m3[(b * 5 + 2 * od + 2) * 4096 + p];
    const float mout = msum > 0.f ? 1.f : 0.f;

    float acc[8];
#pragma unroll
    for (int oc = 0; oc < 8; ++oc) acc[oc] = 0.f;

#pragma unroll 1
    for (int c = 0; c < 64; ++c) {
        const float v0 = h3[((b * 64 + c) * 5 + 2 * od + 0) * 4096 + p];
        const float v1 = h3[((b * 64 + c) * 5 + 2 * od + 1) * 4096 + p];
        const float v2 = h3[((b * 64 + c) * 5 + 2 * od + 2) * 4096 + p];
        const float* __restrict__ wq = wT4 + c * 192 + ocg * 8;  // block-uniform
#pragma unroll
        for (int oc = 0; oc < 8; ++oc) {
            acc[oc] = fmaf(wq[oc], v0,
                      fmaf(wq[64 + oc], v1,
                      fmaf(wq[128 + oc], v2, acc[oc])));
        }
    }

#pragma unroll
    for (int oc = 0; oc < 8; ++oc) {
        const int ocgl = ocg * 8 + oc;
        out[((b * 64 + ocgl) * 2 + od) * 4096 + p] =
            fmaxf(acc[oc] + shb[96 + ocgl], 0.f) * mout;
    }
}

extern "C" void kernel_launch(void* const* d_in, const int* in_sizes, int n_in,
                              void* d_out, int out_size, void* d_ws, size_t ws_size,
                              hipStream_t stream)
{
    const float* vf    = (const float*)d_in[0];
    const int*   coors = (const int*)d_in[1];
    // d_in[2] = batch_size (==2, hardcoded in geometry)
    const float* w1 = (const float*)d_in[3];
    const float* g1 = (const float*)d_in[4];
    const float* b1 = (const float*)d_in[5];
    const float* rm1 = (const float*)d_in[6];
    const float* rv1 = (const float*)d_in[7];
    const float* w2 = (const float*)d_in[8];
    const float* g2 = (const float*)d_in[9];
    const float* b2 = (const float*)d_in[10];
    const float* rm2 = (const float*)d_in[11];
    const float* rv2 = (const float*)d_in[12];
    const float* w3 = (const float*)d_in[13];
    const float* g3 = (const float*)d_in[14];
    const float* b3 = (const float*)d_in[15];
    const float* rm3 = (const float*)d_in[16];
    const float* rv3 = (const float*)d_in[17];
    const float* w4 = (const float*)d_in[18];
    const float* g4 = (const float*)d_in[19];
    const float* b4 = (const float*)d_in[20];
    const float* rm4 = (const float*)d_in[21];
    const float* rv4 = (const float*)d_in[22];

    const int NV = in_sizes[0] / 3;

    float* ws = (float*)d_ws;
    float* y1  = ws;                   // 44,040,192 f  (2,4,21,256,256,4) interleaved
    float* m1  = y1 + 44040192;        //  2,752,512 f  (2,21,256,256)
    float* h2  = m1 + 2752512;         // 11,534,336 f  (2,8,11,128,128,4) interleaved
    float* m2  = h2 + 11534336;        //    360,448 f  (2,11,128,128)
    float* h3  = m2 + 360448;          //  2,621,440 f  (2,64,5,64,64)
    float* m3  = h3 + 2621440;         //     40,960 f  (2,5,64,64)
    float* wT2 = m3 + 40960;           //     13,824 f
    float* wT3 = wT2 + 13824;          //     55,296 f
    float* wT4 = wT3 + 55296;          //     12,288 f
    float* shb = wT4 + 12288;          //        192 f
    unsigned* bm2 = (unsigned*)(shb + 192);  // 360,448 u32 (fully overwritten, no memset)

    // zero the scatter accumulator + mask (y1 and m1 are contiguous)
    hipMemsetAsync(y1, 0, (size_t)(44040192 + 2752512) * sizeof(float), stream);

    repack<<<319, 256, 0, stream>>>(g1, b1, rm1, rv1,
                                    w2, g2, b2, rm2, rv2, w3, g3, b3, rm3, rv3,
                                    w4, g4, b4, rm4, rv4, wT2, wT3, wT4, shb);
    scatter_l1<<<(NV * 16 + 255) / 256, 256, 0, stream>>>(vf, coors, NV, w1, y1, m1);
    build_bm2<<<1408, 256, 0, stream>>>(m1, bm2);
    conv_l2<<<dim3(32, 128, 22), 256, 0, stream>>>((const float4*)y1, bm2,
                                                   (const float4*)wT2, shb, h2, m2);
    conv_l3<<<dim3(16, 8, 10), 128, 0, stream>>>((const float4*)h2, m2, wT3, shb,
                                                 h3, m3);
    conv_l4<<<dim3(16, 32), 256, 0, stream>>>(h3, m3, wT4, shb, (float*)d_out);
}

// Round 13
// 387.131 us; speedup vs baseline: 1.6075x; 1.6075x over previous
//
#include <hip/hip_runtime.h>

#define EPS 1e-3f

// Tensor geometry (fixed for this problem):
// y1 (L1 pre-act): bf16 channel-last (2, 21,256,256, 16)  -- 32 B per cell
// m1: (2,21,256,256) fp32
// h2q: quad-interleaved fp32 (2, 8, 11,128,128, 4)   m2: (2,11,128,128)
// h3:  (2,64,5,64,64)  m3: (2,5,64,64)
// out: (2,64,2,64,64) -> d_out (2,128,64,64) same layout
//
// Lessons encoded:
//  - Block-uniform weight pointers only (scalar s_load path). (r2)
//  - Direct conv beats phase-barrier LDS staging here. (r10)
//  - m1 density ~13.7%, E[taps/px]=3.7, m2 ~98% dense: conv_l2 is effectively
//    DENSE; sparse bitmask/wave-per-px machinery loses to per-wave overhead
//    (r12: 287us vs r11's 132us). r11 thread-per-(px,16oc) is the knee.
//  - Scatter is memory-REQUEST bound: bf16 channel-last y1 (32B/cell) +
//    packed bf16 atomics halve ops and cut lines 4x vs fp32-quad. (r5/r6/r13)
//  - Memset scales with y1 bytes: bf16 halves it. (r13)

// f32 -> bf16 (RNE)
static __device__ __forceinline__ unsigned f2bf(float f) {
    unsigned u = __float_as_uint(f);
    return (u + 0x7FFFu + ((u >> 16) & 1u)) >> 16;
}

// ---------------- Weight repack + BN fold ----------------
// wT2: [tap][cin][oc] 27x16x32; wT3: [tap][cin][oc] 27x32x64; wT4: [(c*3+kz)*64+oc]
// shb: [0..31]=sh2, [32..95]=sh3, [96..159]=sh4, [160..175]=sc1, [176..191]=sh1
__global__ __launch_bounds__(256) void repack(
    const float* __restrict__ g1, const float* __restrict__ b1,
    const float* __restrict__ rm1, const float* __restrict__ rv1,
    const float* __restrict__ w2, const float* __restrict__ g2, const float* __restrict__ b2,
    const float* __restrict__ rm2, const float* __restrict__ rv2,
    const float* __restrict__ w3, const float* __restrict__ g3, const float* __restrict__ b3,
    const float* __restrict__ rm3, const float* __restrict__ rv3,
    const float* __restrict__ w4, const float* __restrict__ g4, const float* __restrict__ b4,
    const float* __restrict__ rm4, const float* __restrict__ rv4,
    float* __restrict__ wT2, float* __restrict__ wT3, float* __restrict__ wT4,
    float* __restrict__ shb)
{
    const int i = blockIdx.x * 256 + threadIdx.x;
    if (i < 13824) {                       // wT2[tap*512 + cin*32 + oc]
        const int tap = i / 512, cin = (i / 32) % 16, oc = i & 31;
        const float inv = g2[oc] * rsqrtf(rv2[oc] + EPS);
        wT2[i] = w2[(oc * 16 + cin) * 27 + tap] * inv;
    } else if (i < 69120) {                // wT3[tap*2048 + cin*64 + oc]
        const int j = i - 13824;
        const int tap = j / 2048, cin = (j / 64) % 32, oc = j & 63;
        const float inv = g3[oc] * rsqrtf(rv3[oc] + EPS);
        wT3[j] = w3[(oc * 32 + cin) * 27 + tap] * inv;
    } else if (i < 81408) {                // wT4[(c*3+kz)*64+oc], 64x3x64
        const int j = i - 69120;
        const int c = j / 192, kz = (j / 64) % 3, oc = j & 63;
        const float inv = g4[oc] * rsqrtf(rv4[oc] + EPS);
        wT4[j] = w4[(oc * 64 + c) * 3 + kz] * inv;
    } else if (i < 81600) {                // shifts + L1 BN scale/shift
        const int j = i - 81408;
        if (j < 32) {
            const float inv = g2[j] * rsqrtf(rv2[j] + EPS);
            shb[j] = b2[j] - rm2[j] * inv;
        } else if (j < 96) {
            const int o = j - 32;
            const float inv = g3[o] * rsqrtf(rv3[o] + EPS);
            shb[j] = b3[o] - rm3[o] * inv;
        } else if (j < 160) {
            const int o = j - 96;
            const float inv = g4[o] * rsqrtf(rv4[o] + EPS);
            shb[j] = b4[o] - rm4[o] * inv;
        } else if (j < 176) {
            const int o = j - 160;
            shb[j] = g1[o] * rsqrtf(rv1[o] + EPS);           // sc1
        } else if (j < 192) {
            const int o = j - 176;
            const float inv = g1[o] * rsqrtf(rv1[o] + EPS);
            shb[j] = b1[o] - rm1[o] * inv;                   // sh1
        }
    }
}

// ---------------- Layer 1: voxel scatter, one thread per (voxel, oc-pair) ----------------
// y1 bf16 channel-last: cell = 32 B contiguous; one packed-bf16 atomic adds 2 ch.
__global__ __launch_bounds__(256) void scatter_l1(
    const float* __restrict__ vf, const int* __restrict__ coors, int NV,
    const float* __restrict__ w1, unsigned short* __restrict__ y1,
    float* __restrict__ m1)
{
    __shared__ float ws[16 * 3 * 27];  // (oc, c, tap)
    for (int e = threadIdx.x; e < 16 * 3 * 27; e += 256) ws[e] = w1[e];
    __syncthreads();

    const int gid = blockIdx.x * 256 + threadIdx.x;
    const int i = gid >> 3;        // voxel
    const int oc2 = gid & 7;       // channel pair
    if (i >= NV) return;
    const int oc = oc2 * 2;

    const int b = coors[4 * i + 0];
    const int z = coors[4 * i + 1];
    const int y = coors[4 * i + 2];
    const int x = coors[4 * i + 3];
    const float f0 = vf[3 * i + 0];
    const float f1 = vf[3 * i + 1];
    const float f2 = vf[3 * i + 2];

    int ozv[2], kzv[2], nz = 0;
    int oyv[2], kyv[2], ny = 0;
    int oxv[2], kxv[2], nx = 0;
#pragma unroll
    for (int k = 0; k < 3; ++k) {
        int t = z + 1 - k;
        if (t >= 0 && !(t & 1)) { int o = t >> 1; if (o < 21) { ozv[nz] = o; kzv[nz] = k; ++nz; } }
    }
#pragma unroll
    for (int k = 0; k < 3; ++k) {
        int t = y + 1 - k;
        if (t >= 0 && !(t & 1)) { int o = t >> 1; if (o < 256) { oyv[ny] = o; kyv[ny] = k; ++ny; } }
    }
#pragma unroll
    for (int k = 0; k < 3; ++k) {
        int t = x + 1 - k;
        if (t >= 0 && !(t & 1)) { int o = t >> 1; if (o < 256) { oxv[nx] = o; kxv[nx] = k; ++nx; } }
    }

    for (int a = 0; a < nz; ++a)
        for (int bb = 0; bb < ny; ++bb)
            for (int c = 0; c < nx; ++c) {
                const int oz = ozv[a], oy = oyv[bb], ox = oxv[c];
                const int tap = (kzv[a] * 3 + kyv[bb]) * 3 + kxv[c];
                const int sp = oz * 65536 + oy * 256 + ox;
                if (oc2 == 0) m1[b * 1376256 + sp] = 1.0f;
                const float s0 = ws[oc * 81 + tap] * f0 + ws[oc * 81 + 27 + tap] * f1 +
                                 ws[oc * 81 + 54 + tap] * f2;
                const float s1 = ws[(oc + 1) * 81 + tap] * f0 +
                                 ws[(oc + 1) * 81 + 27 + tap] * f1 +
                                 ws[(oc + 1) * 81 + 54 + tap] * f2;
                const unsigned pk = f2bf(s0) | (f2bf(s1) << 16);
                unsigned* addr = (unsigned*)(y1 + (size_t)(b * 1376256 + sp) * 16 +
                                             oc2 * 2);
                asm volatile("global_atomic_pk_add_bf16 %0, %1, off"
                             : : "v"(addr), "v"(pk) : "memory");
            }
}

// ---------------- Layer 2: DIRECT conv 16->32, k3, s2, pad(1,1,1) ----------------
// One thread per (output px, 16-oc group). No LDS/barriers. 27 mask values
// preloaded; active taps read the cell's 16 bf16 cin (2x16B loads) + 256 FMA.
// Writes h2 quad-interleaved (fp32) for conv_l3's vector loads.
__global__ __launch_bounds__(128) __attribute__((amdgpu_waves_per_eu(4, 8)))
void conv_l2(
    const uint4* __restrict__ y1b, const float* __restrict__ m1,
    const float* __restrict__ wT2, const float* __restrict__ shb,
    float4* __restrict__ h2q, float* __restrict__ m2)
{
    const int tid = threadIdx.x;
    const int tx = tid & 15, ty = tid >> 4;            // 16 x 8 px tile
    const int ocg = blockIdx.x >> 3;                   // 0..1 (16 oc each)
    const int ox = (blockIdx.x & 7) * 16 + tx, oy = blockIdx.y * 8 + ty;
    const int bz = blockIdx.z;
    const int b = bz / 11, oz = bz % 11;
    const int iz0 = 2 * oz - 1, iyb = 2 * oy - 1, ixb = 2 * ox - 1;

    // L1 BN params as uniforms -> SGPRs
    float sc1[16], sh1[16];
#pragma unroll
    for (int c = 0; c < 16; ++c) { sc1[c] = shb[160 + c]; sh1[c] = shb[176 + c]; }

    // preload 27 mask values (independent loads pipeline)
    float mv[27];
    float msum = 0.f;
#pragma unroll
    for (int kz = 0; kz < 3; ++kz) {
        const int iz = iz0 + kz;
#pragma unroll
        for (int ky = 0; ky < 3; ++ky) {
            const int iy = iyb + ky;
#pragma unroll
            for (int kx = 0; kx < 3; ++kx) {
                const int ix = ixb + kx;
                float m = 0.f;
                if ((unsigned)iz < 21u && (unsigned)iy < 256u && (unsigned)ix < 256u)
                    m = m1[b * 1376256 + iz * 65536 + iy * 256 + ix];
                mv[(kz * 3 + ky) * 3 + kx] = m;
                msum += m;
            }
        }
    }

    float acc[16];
#pragma unroll
    for (int oc = 0; oc < 16; ++oc) acc[oc] = 0.f;

#pragma unroll 1
    for (int kz = 0; kz < 3; ++kz) {
        const int iz = iz0 + kz;
#pragma unroll 1
        for (int ky = 0; ky < 3; ++ky) {
            const int iy = iyb + ky;
#pragma unroll 1
            for (int kx = 0; kx < 3; ++kx) {
                const int tap = (kz * 3 + ky) * 3 + kx;
                if (mv[tap] > 0.f) {
                    const int ix = ixb + kx;
                    const int cb = (b * 1376256 + iz * 65536 + iy * 256 + ix) * 2;
                    const uint4 u0 = y1b[cb];
                    const uint4 u1 = y1b[cb + 1];
                    const float* __restrict__ wq = wT2 + tap * 512 + ocg * 16; // uniform
                    const unsigned d[8] = {u0.x, u0.y, u0.z, u0.w,
                                           u1.x, u1.y, u1.z, u1.w};
#pragma unroll
                    for (int j = 0; j < 8; ++j) {
                        const int c0 = 2 * j;
                        const float vlo = __uint_as_float(d[j] << 16);
                        const float vhi = __uint_as_float(d[j] & 0xFFFF0000u);
                        const float v0 = fmaxf(vlo * sc1[c0] + sh1[c0], 0.f);
                        const float v1 = fmaxf(vhi * sc1[c0 + 1] + sh1[c0 + 1], 0.f);
#pragma unroll
                        for (int oc = 0; oc < 16; ++oc) {
                            acc[oc] = fmaf(wq[c0 * 32 + oc], v0,
                                      fmaf(wq[(c0 + 1) * 32 + oc], v1, acc[oc]));
                        }
                    }
                }
            }
        }
    }

    const float mout = msum > 0.f ? 1.f : 0.f;
    const int spo = oz * 16384 + oy * 128 + ox;
    if (ocg == 0) m2[b * 180224 + spo] = mout;
#pragma unroll
    for (int lq = 0; lq < 4; ++lq) {
        const int q = ocg * 4 + lq;
        float4 o;
        o.x = fmaxf(acc[lq * 4 + 0] + shb[ocg * 16 + lq * 4 + 0], 0.f) * mout;
        o.y = fmaxf(acc[lq * 4 + 1] + shb[ocg * 16 + lq * 4 + 1], 0.f) * mout;
        o.z = fmaxf(acc[lq * 4 + 2] + shb[ocg * 16 + lq * 4 + 2], 0.f) * mout;
        o.w = fmaxf(acc[lq * 4 + 3] + shb[ocg * 16 + lq * 4 + 3], 0.f) * mout;
        h2q[(b * 8 + q) * 180224 + spo] = o;
    }
}

// ---------------- Layer 3: DIRECT conv 32->64, k3, s2, pad(0,1,1) ----------------
// One thread per (output px, 8-oc group). Full 32-cin accumulation per thread;
// fused BN/ReLU/mask epilogue. h2 is dense-masked, so only edge-OOB skip.
__global__ __launch_bounds__(128) __attribute__((amdgpu_waves_per_eu(4, 8)))
void conv_l3(
    const float4* __restrict__ h2q, const float* __restrict__ m2,
    const float* __restrict__ wT3, const float* __restrict__ shb,
    float* __restrict__ h3, float* __restrict__ m3)
{
    const int tid = threadIdx.x;
    const int tx = tid & 15, ty = tid >> 4;            // 16 x 8 px tile
    const int ocg = blockIdx.x >> 2;                   // 0..7 (8 oc each)
    const int ox = (blockIdx.x & 3) * 16 + tx, oy = blockIdx.y * 8 + ty;
    const int bz = blockIdx.z;
    const int b = bz / 5, oz = bz % 5;
    const int iz0 = 2 * oz, iyb = 2 * oy - 1, ixb = 2 * ox - 1;   // z pad 0

    float acc[8];
#pragma unroll
    for (int oc = 0; oc < 8; ++oc) acc[oc] = 0.f;
    float msum = 0.f;

#pragma unroll 1
    for (int kz = 0; kz < 3; ++kz) {
        const int iz = iz0 + kz;                       // always in [0,10]
#pragma unroll 1
        for (int ky = 0; ky < 3; ++ky) {
            const int iy = iyb + ky;
#pragma unroll 1
            for (int kx = 0; kx < 3; ++kx) {
                const int ix = ixb + kx;
                const bool ok = (unsigned)iy < 128u && (unsigned)ix < 128u;
                if (ok) {
                    const int sp = iz * 16384 + iy * 128 + ix;
                    msum += m2[b * 180224 + sp];
                    const int tap = (kz * 3 + ky) * 3 + kx;
                    const float* __restrict__ wq = wT3 + tap * 2048 + ocg * 8; // uniform
#pragma unroll
                    for (int q = 0; q < 8; ++q) {
                        const float4 a = h2q[(b * 8 + q) * 180224 + sp];
                        const int c0 = q * 4;
#pragma unroll
                        for (int oc = 0; oc < 8; ++oc) {
                            acc[oc] = fmaf(wq[(c0 + 0) * 64 + oc], a.x,
                                      fmaf(wq[(c0 + 1) * 64 + oc], a.y,
                                      fmaf(wq[(c0 + 2) * 64 + oc], a.z,
                                      fmaf(wq[(c0 + 3) * 64 + oc], a.w, acc[oc]))));
                        }
                    }
                }
            }
        }
    }

    const float mout = msum > 0.f ? 1.f : 0.f;
    const int spo = oz * 4096 + oy * 64 + ox;
    if (ocg == 0) m3[b * 20480 + spo] = mout;
#pragma unroll
    for (int oc = 0; oc < 8; ++oc) {
        const int ocg8 = ocg * 8 + oc;
        h3[(b * 64 + ocg8) * 20480 + spo] =
            fmaxf(acc[oc] + shb[32 + ocg8], 0.f) * mout;
    }
}

// ---------------- Layer 4: conv 64->64, k(3,1,1), s(2,1,1), pad 0 ----------------
__global__ __launch_bounds__(256) __attribute__((amdgpu_waves_per_eu(4, 8)))
void conv_l4(
    const float* __restrict__ h3, const float* __restrict__ m3,
    const float* __restrict__ wT4, const float* __restrict__ shb,
    float* __restrict__ out)
{
    const int p = blockIdx.x * 256 + threadIdx.x;  // 0..4095 spatial
    const int bo = blockIdx.y;
    const int b = bo >> 4, od = (bo >> 3) & 1, ocg = bo & 7;

    const float msum = m3[(b * 5 + 2 * od + 0) * 4096 + p] +
                       m3[(b * 5 + 2 * od + 1) * 4096 + p] +
                       m3[(b * 5 + 2 * od + 2) * 4096 + p];
    const float mout = msum > 0.f ? 1.f : 0.f;

    float acc[8];
#pragma unroll
    for (int oc = 0; oc < 8; ++oc) acc[oc] = 0.f;

#pragma unroll 1
    for (int c = 0; c < 64; ++c) {
        const float v0 = h3[((b * 64 + c) * 5 + 2 * od + 0) * 4096 + p];
        const float v1 = h3[((b * 64 + c) * 5 + 2 * od + 1) * 4096 + p];
        const float v2 = h3[((b * 64 + c) * 5 + 2 * od + 2) * 4096 + p];
        const float* __restrict__ wq = wT4 + c * 192 + ocg * 8;  // block-uniform
#pragma unroll
        for (int oc = 0; oc < 8; ++oc) {
            acc[oc] = fmaf(wq[oc], v0,
                      fmaf(wq[64 + oc], v1,
                      fmaf(wq[128 + oc], v2, acc[oc])));
        }
    }

#pragma unroll
    for (int oc = 0; oc < 8; ++oc) {
        const int ocgl = ocg * 8 + oc;
        out[((b * 64 + ocgl) * 2 + od) * 4096 + p] =
            fmaxf(acc[oc] + shb[96 + ocgl], 0.f) * mout;
    }
}

extern "C" void kernel_launch(void* const* d_in, const int* in_sizes, int n_in,
                              void* d_out, int out_size, void* d_ws, size_t ws_size,
                              hipStream_t stream)
{
    const float* vf    = (const float*)d_in[0];
    const int*   coors = (const int*)d_in[1];
    // d_in[2] = batch_size (==2, hardcoded in geometry)
    const float* w1 = (const float*)d_in[3];
    const float* g1 = (const float*)d_in[4];
    const float* b1 = (const float*)d_in[5];
    const float* rm1 = (const float*)d_in[6];
    const float* rv1 = (const float*)d_in[7];
    const float* w2 = (const float*)d_in[8];
    const float* g2 = (const float*)d_in[9];
    const float* b2 = (const float*)d_in[10];
    const float* rm2 = (const float*)d_in[11];
    const float* rv2 = (const float*)d_in[12];
    const float* w3 = (const float*)d_in[13];
    const float* g3 = (const float*)d_in[14];
    const float* b3 = (const float*)d_in[15];
    const float* rm3 = (const float*)d_in[16];
    const float* rv3 = (const float*)d_in[17];
    const float* w4 = (const float*)d_in[18];
    const float* g4 = (const float*)d_in[19];
    const float* b4 = (const float*)d_in[20];
    const float* rm4 = (const float*)d_in[21];
    const float* rv4 = (const float*)d_in[22];

    const int NV = in_sizes[0] / 3;

    float* ws = (float*)d_ws;
    float* y1  = ws;                   // 22,020,096 f-slots = bf16 (2,21,256,256,16)
    float* m1  = y1 + 22020096;        //  2,752,512 f  (2,21,256,256)
    float* h2q = m1 + 2752512;         // 11,534,336 f  (2,8,11,128,128,4) interleaved
    float* m2  = h2q + 11534336;       //    360,448 f  (2,11,128,128)
    float* h3  = m2 + 360448;          //  2,621,440 f  (2,64,5,64,64)
    float* m3  = h3 + 2621440;         //     40,960 f  (2,5,64,64)
    float* wT2 = m3 + 40960;           //     13,824 f
    float* wT3 = wT2 + 13824;          //     55,296 f
    float* wT4 = wT3 + 55296;          //     12,288 f
    float* shb = wT4 + 12288;          //        192 f

    // zero the scatter accumulator (bf16) + mask (contiguous)
    hipMemsetAsync(y1, 0, (size_t)(22020096 + 2752512) * sizeof(float), stream);

    repack<<<319, 256, 0, stream>>>(g1, b1, rm1, rv1,
                                    w2, g2, b2, rm2, rv2, w3, g3, b3, rm3, rv3,
                                    w4, g4, b4, rm4, rv4, wT2, wT3, wT4, shb);
    scatter_l1<<<(NV * 8 + 255) / 256, 256, 0, stream>>>(vf, coors, NV, w1,
                                                         (unsigned short*)y1, m1);
    conv_l2<<<dim3(16, 16, 22), 128, 0, stream>>>((const uint4*)y1, m1, wT2, shb,
                                                  (float4*)h2q, m2);
    conv_l3<<<dim3(32, 8, 10), 128, 0, stream>>>((const float4*)h2q, m2, wT3, shb,
                                                 h3, m3);
    conv_l4<<<dim3(16, 32), 256, 0, stream>>>(h3, m3, wT4, shb, (float*)d_out);
}